// Round 7
// baseline (178.722 us; speedup 1.0000x reference)
//
#include <hip/hip_runtime.h>
#include <hip/hip_bf16.h>

// y[b, c] = (sum_k x[b,k] * W[c % 512, k]) + bias[c]
// R12: R11 skeleton (128x128 tile, split-K=4 -> 512 blocks = 2/CU, XCD
// co-location, no-sync partial-slot combine kernel) with the x fp32->bf16
// convert FUSED into the GEMM:
//   - A staged as RAW fp32 via global_load_lds; converted to bf16 in-register
//     after ds_read (R7-proven paired-f4 + v_perm path). The 96-MB x-convert
//     dispatch is gone; only the 3-us W convert remains.
//   - BK=32 so the 3-stage ring stays at 72 KB (A 16 KB fp32 + B 8 KB bf16
//     per stage) -> 2 blocks/CU, the residency the DMA engine rate needs
//     (R10 showed ~3x rate collapse at 1 block/CU).
//   - 6 DMA insts/wave/iter -> counted s_waitcnt vmcnt(6) (R7's count),
//     NITER=32, depth-2 prefetch, single barrier/iter (R5/R7-proven ring).
// Model (holds on R5/R7/R8/R10/R11 within ~10%): global_load_lds sustains
// ~20 B/cy/CU at 2 blocks/CU -> K-loop = 1.5 MB/CU / 48 GB/s ~= 31 us.
//   gemm ~36 us (+8 vs R11), convert 25 -> 3 us (-22), total ~137 us.

typedef __bf16 bf8 __attribute__((ext_vector_type(8)));
typedef float f4 __attribute__((ext_vector_type(4)));
typedef unsigned int uint;
typedef unsigned short ushort;

constexpr int M = 4096;
constexpr int K = 4096;
constexpr int NS = 512;
constexpr int OUTF = 4096;
constexpr int BM = 128, BN = 128, BK = 32;
constexpr int SPLITS = 4;
constexpr int KSPL = K / SPLITS;    // 1024
constexpr int NITER = KSPL / BK;    // 32
constexpr int MT = M / BM;          // 32
constexpr int NT = NS / BN;         // 4

#define PERM_HI2(hi, lo) __builtin_amdgcn_perm((hi), (lo), 0x07060302u)
// s_waitcnt imm: vmcnt[3:0]|expcnt[6:4]|lgkmcnt[11:8]|vmcnt[15:14]
#define WAITCNT_VM6 0xF76   // vmcnt<=6: tile kk's 6 DMAs drained, kk+1 in flight
#define WAITCNT_VM0 0xF70

__device__ __forceinline__ void async16(const void* g, void* l) {
  __builtin_amdgcn_global_load_lds(
      (const __attribute__((address_space(1))) void*)g,
      (__attribute__((address_space(3))) void*)l, 16, 0, 0);
}

// W only: fp32 -> bf16 (truncate), 8 elems/thread. 512*4096/8/256 = 1024 blocks.
__global__ __launch_bounds__(256)
void convert_w(const float* __restrict__ w, ushort* __restrict__ wb) {
  const size_t i = (size_t)blockIdx.x * 256 + threadIdx.x;
  const float* src = w + i * 8;
  ushort* dst = wb + i * 8;
  const uint4 a = *reinterpret_cast<const uint4*>(src);
  const uint4 b = *reinterpret_cast<const uint4*>(src + 4);
  uint4 o;
  o.x = PERM_HI2(a.y, a.x); o.y = PERM_HI2(a.w, a.z);
  o.z = PERM_HI2(b.y, b.x); o.w = PERM_HI2(b.w, b.z);
  *reinterpret_cast<uint4*>(dst) = o;
}

__global__ __launch_bounds__(256, 2)
void gemm_kernel(const float* __restrict__ x, const ushort* __restrict__ wb,
                 float* __restrict__ out) {
  __shared__ __align__(16) float  As[3][BM * BK];   // fp32 A, 16 KB/stage
  __shared__ __align__(16) ushort Bs[3][BN * BK];   // bf16 B,  8 KB/stage
  // 72 KB total (R7-proven size) -> 2 blocks/CU

  // block map (R11): b = (mt&7) + 8*((mt>>3)*16 + sp*4 + nt)
  // -> the 16 blocks of one mt share b&7 (one XCD), x-slab fetched once/XCD.
  const int b   = blockIdx.x;          // 512 blocks
  const int low = b & 7, h = b >> 3;   // h in [0,64)
  const int mt  = (h >> 4) * 8 + low;  // 0..31
  const int sp  = (h >> 2) & 3;        // split 0..3
  const int nt  = h & 3;               // 0..3

  const int tid  = threadIdx.x;
  const int wv   = tid >> 6;           // 0..3
  const int lane = tid & 63;
  const int lr   = lane & 15;
  const int lq   = lane >> 4;

  // A DMA: tile = 128 rows x 32 fp32 = 1024 16B-chunks (8/row); 4 insts/wave.
  // LDS chunk c holds global chunk ((c&7) ^ (row&7)) of row (c>>3).
  int goffA[4], llocA[4];
#pragma unroll
  for (int j = 0; j < 4; ++j) {
    const int c = (wv * 4 + j) * 64 + lane;
    const int r = c >> 3;
    const int g = (c & 7) ^ (r & 7);
    goffA[j] = r * K + g * 4;       // float units
    llocA[j] = c * 4;               // float units, linear dest
  }
  // B DMA: tile = 128 rows x 32 bf16 = 512 16B-chunks (4/row); 2 insts/wave.
  // LDS chunk c holds global chunk ((c&3) ^ (row&3)) of row (c>>2).
  int goffB[2], llocB[2];
#pragma unroll
  for (int j = 0; j < 2; ++j) {
    const int c = (wv * 2 + j) * 64 + lane;
    const int r = c >> 2;
    const int g = (c & 3) ^ (r & 3);
    goffB[j] = r * K + g * 8;       // ushort units
    llocB[j] = c * 8;               // ushort units, linear dest
  }

  const float*  xT = x  + (size_t)(mt * BM) * K + sp * KSPL;
  const ushort* wT = wb + (size_t)(nt * BN) * K + sp * KSPL;

  auto issue = [&](int tile, int stg) {
    const int ko = tile * BK;
#pragma unroll
    for (int j = 0; j < 4; ++j) async16(xT + ko + goffA[j], &As[stg][llocA[j]]);
#pragma unroll
    for (int j = 0; j < 2; ++j) async16(wT + ko + goffB[j], &Bs[stg][llocB[j]]);
  };

  const int wm = (wv & 1) * 64;        // 2x2 wave grid, wave tile 64x64
  const int wn = (wv >> 1) * 64;

  f4 acc[4][4] = {};

  // prologue: tiles 0,1 into stages 0,1 (6 DMAs/wave each)
  issue(0, 0);
  issue(1, 1);

  int st = 0;
  for (int kk = 0; kk < NITER; ++kk) {
    if (kk + 1 < NITER) __builtin_amdgcn_s_waitcnt(WAITCNT_VM6);
    else                __builtin_amdgcn_s_waitcnt(WAITCNT_VM0);
    __builtin_amdgcn_s_barrier();      // publish tile kk (stage st)
    asm volatile("" ::: "memory");

    // issue tile kk+2 into stage (kk+2)%3 == (kk-1)%3 (fully read; safe)
    if (kk + 2 < NITER) {
      int s2 = st + 2; if (s2 >= 3) s2 -= 3;
      issue(kk + 2, s2);
    }

    const float*  aT = As[st];
    const ushort* bT = Bs[st];
    bf8 af[4], bfv[4];
#pragma unroll
    for (int mf = 0; mf < 4; ++mf) {
      // lane needs fp32 chunks 2lq, 2lq+1 of its row; slot = chunk^(row&7).
      const int row = wm + mf * 16 + lr;
      const int ca  = (2 * lq) ^ (lr & 7);
      const f4 a0 = *reinterpret_cast<const f4*>(&aT[row * BK + ca * 4]);
      const f4 a1 = *reinterpret_cast<const f4*>(&aT[row * BK + (ca ^ 1) * 4]);
      const uint* u0 = reinterpret_cast<const uint*>(&a0);
      const uint* u1 = reinterpret_cast<const uint*>(&a1);
      uint4 p;
      p.x = PERM_HI2(u0[1], u0[0]); p.y = PERM_HI2(u0[3], u0[2]);
      p.z = PERM_HI2(u1[1], u1[0]); p.w = PERM_HI2(u1[3], u1[2]);
      af[mf] = __builtin_bit_cast(bf8, p);
    }
#pragma unroll
    for (int nf = 0; nf < 4; ++nf) {
      // lane needs bf16 chunk lq of its row; slot = lq^(row&3).
      const int rowb = wn + nf * 16 + lr;
      const int sb   = lq ^ (lr & 3);
      bfv[nf] = *reinterpret_cast<const bf8*>(&bT[rowb * BK + sb * 8]);
    }
#pragma unroll
    for (int mf = 0; mf < 4; ++mf)
#pragma unroll
      for (int nf = 0; nf < 4; ++nf)
        acc[mf][nf] = __builtin_amdgcn_mfma_f32_16x16x32_bf16(af[mf], bfv[nf], acc[mf][nf], 0, 0, 0);
    asm volatile("" ::: "memory");

    if (++st >= 3) st = 0;
  }

  // ---- epilogue: write fp32 partial into replica slot #sp of out (R11) ----
  // C/D layout (16x16x32, verified): row = wm+mf*16+lq*4+r, col = wn+nf*16+lr.
  float* pb = out + (size_t)(mt * BM) * OUTF + sp * NS + nt * BN;
#pragma unroll
  for (int mf = 0; mf < 4; ++mf)
#pragma unroll
    for (int nf = 0; nf < 4; ++nf)
#pragma unroll
      for (int r = 0; r < 4; ++r)
        pb[(size_t)(wm + mf * 16 + lq * 4 + r) * OUTF + wn + nf * 16 + lr] =
            acc[mf][nf][r];
}

// y[r][rep][c] = sum_{sp<4} out[r][sp][c] + bias[rep][c], rep = 0..7.
// In-place safe: thread (r,c4) reads only addresses it alone writes.
__global__ __launch_bounds__(256)
void combine_kernel(const float* __restrict__ bias, float* __restrict__ out) {
  const int idx = blockIdx.x * 256 + threadIdx.x;   // 2048 blocks -> 524288
  const int row = idx >> 7;            // 0..4095
  const int c4  = idx & 127;           // float4-col within 512
  float* orow = out + (size_t)row * OUTF;
  float4 s;
  {
    const float4 p0 = *reinterpret_cast<const float4*>(orow + 0 * NS + c4 * 4);
    const float4 p1 = *reinterpret_cast<const float4*>(orow + 1 * NS + c4 * 4);
    const float4 p2 = *reinterpret_cast<const float4*>(orow + 2 * NS + c4 * 4);
    const float4 p3 = *reinterpret_cast<const float4*>(orow + 3 * NS + c4 * 4);
    s.x = (p0.x + p1.x) + (p2.x + p3.x);
    s.y = (p0.y + p1.y) + (p2.y + p3.y);
    s.z = (p0.z + p1.z) + (p2.z + p3.z);
    s.w = (p0.w + p1.w) + (p2.w + p3.w);
  }
  const float4* bias4 = reinterpret_cast<const float4*>(bias);
#pragma unroll
  for (int rep = 0; rep < 8; ++rep) {
    const float4 bb = bias4[rep * 128 + c4];
    float4 o;
    o.x = s.x + bb.x; o.y = s.y + bb.y;
    o.z = s.z + bb.z; o.w = s.w + bb.w;
    *reinterpret_cast<float4*>(orow + rep * NS + c4 * 4) = o;
  }
}

extern "C" void kernel_launch(void* const* d_in, const int* in_sizes, int n_in,
                              void* d_out, int out_size, void* d_ws, size_t ws_size,
                              hipStream_t stream) {
  (void)in_sizes; (void)n_in; (void)out_size; (void)ws_size;
  const float* x    = (const float*)d_in[0];
  const float* w    = (const float*)d_in[1];
  const float* bias = (const float*)d_in[2];
  float* out = (float*)d_out;

  ushort* wb = (ushort*)d_ws;          // 4 MB bf16 W (ws >= 4 MB)

  constexpr int convw_blocks = (int)((size_t)NS * K / 8 / 256);  // 1024
  convert_w<<<dim3(convw_blocks), dim3(256), 0, stream>>>(w, wb);
  gemm_kernel<<<dim3(MT * NT * SPLITS), dim3(256), 0, stream>>>(x, wb, out);
  combine_kernel<<<dim3(M * (NS / 4) / 256), dim3(256), 0, stream>>>(bias, out);
}

// Round 8
// 150.430 us; speedup vs baseline: 1.1881x; 1.1881x over previous
//
#include <hip/hip_runtime.h>
#include <hip/hip_bf16.h>

// y[b, c] = (sum_k x[b,k] * W[c % 512, k]) + bias[c]
// R13: R11 (best, 150.8us: 128x128 tile, split-K=4 -> 512 blocks, bf16 DMA
// staging, 2-stage 64KB ring, no-sync partial-slot combine) + PRODUCER-
// CONSUMER WAVE SPECIALIZATION:
//   - rate data: m97 ~21 B/cy/CU of global_load_lds at ~12 issuing waves/CU;
//     R11 15.6 at 8; R10 ~6 at 8 waves in one lockstep block. Model: DMA
//     throughput scales with wave-queues issuing across barrier gaps.
//   - blocks go 256 -> 512 threads: waves 0-3 = R11 consumers VERBATIM
//     (reads/swizzle/MFMA/epilogue unchanged); waves 4-7 = pure producers
//     owning all 32 DMA insts/iter + the counted vmcnt(8) waits.
//   - consumers never vmcnt-wait; producers hold the same guarantee R11 had
//     (vm8 after issuing kk+2 => tile kk+1 landed before its publish barrier).
//   - 16 waves/CU (2 blocks) cover each other's barrier drain gaps.
// Fusion attempts are CLOSED: convert-x costs only ~12us (R11-R12 diff);
// every fusion (R7/R9/R12) cost >=+30us on gemm. bf16 staging is final.

typedef __bf16 bf8 __attribute__((ext_vector_type(8)));
typedef float f4 __attribute__((ext_vector_type(4)));
typedef unsigned int uint;
typedef unsigned short ushort;

constexpr int M = 4096;
constexpr int K = 4096;
constexpr int NS = 512;
constexpr int OUTF = 4096;
constexpr int BM = 128, BN = 128, BK = 64;
constexpr int SPLITS = 4;
constexpr int KSPL = K / SPLITS;    // 1024
constexpr int NITER = KSPL / BK;    // 16
constexpr int MT = M / BM;          // 32
constexpr int NT = NS / BN;         // 4

#define PERM_HI2(hi, lo) __builtin_amdgcn_perm((hi), (lo), 0x07060302u)
// s_waitcnt imm: vmcnt[3:0]|expcnt[6:4]|lgkmcnt[11:8]|vmcnt[15:14]
#define WAITCNT_VM8 0xF78   // vmcnt<=8: kk+1's 8 DMAs drained, kk+2's in flight
#define WAITCNT_VM0 0xF70

__device__ __forceinline__ void async16(const ushort* g, ushort* l) {
  __builtin_amdgcn_global_load_lds(
      (const __attribute__((address_space(1))) void*)g,
      (__attribute__((address_space(3))) void*)l, 16, 0, 0);
}

// fp32 -> bf16 (truncate), 8 elems/thread; covers x then W exactly (R0-proven).
__global__ __launch_bounds__(256)
void convert_kernel(const float* __restrict__ x, const float* __restrict__ w,
                    ushort* __restrict__ xb, ushort* __restrict__ wb) {
  const size_t i = (size_t)blockIdx.x * 256 + threadIdx.x;
  constexpr size_t NX = (size_t)M * K / 8;
  const float* src;
  ushort* dst;
  if (i < NX) { src = x + i * 8; dst = xb + i * 8; }
  else        { const size_t j = i - NX; src = w + j * 8; dst = wb + j * 8; }
  const uint4 a = *reinterpret_cast<const uint4*>(src);
  const uint4 b = *reinterpret_cast<const uint4*>(src + 4);
  uint4 o;
  o.x = PERM_HI2(a.y, a.x); o.y = PERM_HI2(a.w, a.z);
  o.z = PERM_HI2(b.y, b.x); o.w = PERM_HI2(b.w, b.z);
  *reinterpret_cast<uint4*>(dst) = o;
}

__global__ __launch_bounds__(512, 4)
void gemm_kernel(const ushort* __restrict__ xb, const ushort* __restrict__ wb,
                 float* __restrict__ out) {
  __shared__ __align__(16) ushort As[2][BM * BK];   // 16 KB/stage
  __shared__ __align__(16) ushort Bs[2][BN * BK];   // 16 KB/stage  -> 64 KB

  // block map (R11): b = (mt&7) + 8*((mt>>3)*16 + sp*4 + nt)
  // -> the 16 blocks of one mt share b&7 (one XCD), x-slab fetched once/XCD.
  const int b   = blockIdx.x;          // 512 blocks
  const int low = b & 7, h = b >> 3;   // h in [0,64)
  const int mt  = (h >> 4) * 8 + low;  // 0..31
  const int sp  = (h >> 2) & 3;        // split 0..3
  const int nt  = h & 3;               // 0..3

  const int tid  = threadIdx.x;
  const int wv   = tid >> 6;           // 0..7: 0-3 consumers, 4-7 producers
  const int lane = tid & 63;
  const int lr   = lane & 15;
  const int lq   = lane >> 4;
  const bool producer = wv >= 4;

  const ushort* xT = xb + (size_t)(mt * BM) * K + sp * KSPL;
  const ushort* wT = wb + (size_t)(nt * BN) * K + sp * KSPL;

  // Producer DMA map (R11's formula with pw = wv-4): per matrix the tile is
  // 1024 16B-chunks (8/row); LDS chunk c holds global chunk ((c&7)^(r&7)) of
  // row r = c>>3 (linear dest, swizzled source). 4 A + 4 B insts per p-wave.
  int goff[4], lloc[4];
  {
    const int pw = wv & 3;
#pragma unroll
    for (int j = 0; j < 4; ++j) {
      const int c = (pw * 4 + j) * 64 + lane;
      const int r = c >> 3;
      const int g = (c & 7) ^ (r & 7);
      goff[j] = r * K + g * 8;
      lloc[j] = c * 8;
    }
  }
  auto issue = [&](int tile, int stg) {
    const int ko = tile * BK;
#pragma unroll
    for (int j = 0; j < 4; ++j) {
      async16(xT + ko + goff[j], &As[stg][lloc[j]]);
      async16(wT + ko + goff[j], &Bs[stg][lloc[j]]);
    }
  };

  // Consumer geometry (R11 verbatim): 2x2 wave grid, wave tile 64x64.
  const int wm = (wv & 1) * 64;
  const int wn = ((wv >> 1) & 1) * 64;

  f4 acc[4][4] = {};

  // prologue: producers stage tiles 0,1; vm8 leaves tile 1 in flight.
  if (producer) {
    issue(0, 0);
    issue(1, 1);
    __builtin_amdgcn_s_waitcnt(WAITCNT_VM8);   // tile 0 landed
  }
  __builtin_amdgcn_s_barrier();
  asm volatile("" ::: "memory");

  int st = 0;
  for (int kk = 0; kk < NITER; ++kk) {
    // entering: tile kk resident in stage st (published by the barrier above)
    if (!producer) {
      const ushort* aT = As[st];
      const ushort* bT = Bs[st];
#pragma unroll
      for (int t = 0; t < 2; ++t) {
        const int sc = ((t * 4 + lq) ^ (lr & 7)) * 8;   // R5-proven read swizzle
        bf8 af[4], bfv[4];
#pragma unroll
        for (int mf = 0; mf < 4; ++mf)
          af[mf] = *reinterpret_cast<const bf8*>(&aT[(wm + mf * 16 + lr) * BK + sc]);
#pragma unroll
        for (int nf = 0; nf < 4; ++nf)
          bfv[nf] = *reinterpret_cast<const bf8*>(&bT[(wn + nf * 16 + lr) * BK + sc]);
#pragma unroll
        for (int mf = 0; mf < 4; ++mf)
#pragma unroll
          for (int nf = 0; nf < 4; ++nf)
            acc[mf][nf] = __builtin_amdgcn_mfma_f32_16x16x32_bf16(af[mf], bfv[nf], acc[mf][nf], 0, 0, 0);
      }
      asm volatile("" ::: "memory");
    }
    __builtin_amdgcn_s_barrier();      // stage st fully read
    asm volatile("" ::: "memory");

    if (producer) {
      if (kk + 2 < NITER) {
        issue(kk + 2, st);             // stage st now reusable
        __builtin_amdgcn_s_waitcnt(WAITCNT_VM8);   // tile kk+1 landed
      } else if (kk + 1 < NITER) {
        __builtin_amdgcn_s_waitcnt(WAITCNT_VM0);   // drain: kk+1 landed
      }
    }
    __builtin_amdgcn_s_barrier();      // publish tile kk+1 (stage st^1)
    asm volatile("" ::: "memory");
    st ^= 1;
  }

  if (producer) return;

  // ---- epilogue: write fp32 partial into replica slot #sp of out (R11) ----
  // C/D layout (16x16x32, verified): row = wm+mf*16+lq*4+r, col = wn+nf*16+lr.
  float* pb = out + (size_t)(mt * BM) * OUTF + sp * NS + nt * BN;
#pragma unroll
  for (int mf = 0; mf < 4; ++mf)
#pragma unroll
    for (int nf = 0; nf < 4; ++nf)
#pragma unroll
      for (int r = 0; r < 4; ++r)
        pb[(size_t)(wm + mf * 16 + lq * 4 + r) * OUTF + wn + nf * 16 + lr] =
            acc[mf][nf][r];
}

// y[r][rep][c] = sum_{sp<4} out[r][sp][c] + bias[rep][c], rep = 0..7.
// In-place safe: thread (r,c4) reads only addresses it alone writes.
__global__ __launch_bounds__(256)
void combine_kernel(const float* __restrict__ bias, float* __restrict__ out) {
  const int idx = blockIdx.x * 256 + threadIdx.x;   // 2048 blocks -> 524288
  const int row = idx >> 7;            // 0..4095
  const int c4  = idx & 127;           // float4-col within 512
  float* orow = out + (size_t)row * OUTF;
  float4 s;
  {
    const float4 p0 = *reinterpret_cast<const float4*>(orow + 0 * NS + c4 * 4);
    const float4 p1 = *reinterpret_cast<const float4*>(orow + 1 * NS + c4 * 4);
    const float4 p2 = *reinterpret_cast<const float4*>(orow + 2 * NS + c4 * 4);
    const float4 p3 = *reinterpret_cast<const float4*>(orow + 3 * NS + c4 * 4);
    s.x = (p0.x + p1.x) + (p2.x + p3.x);
    s.y = (p0.y + p1.y) + (p2.y + p3.y);
    s.z = (p0.z + p1.z) + (p2.z + p3.z);
    s.w = (p0.w + p1.w) + (p2.w + p3.w);
  }
  const float4* bias4 = reinterpret_cast<const float4*>(bias);
#pragma unroll
  for (int rep = 0; rep < 8; ++rep) {
    const float4 bb = bias4[rep * 128 + c4];
    float4 o;
    o.x = s.x + bb.x; o.y = s.y + bb.y;
    o.z = s.z + bb.z; o.w = s.w + bb.w;
    *reinterpret_cast<float4*>(orow + rep * NS + c4 * 4) = o;
  }
}

extern "C" void kernel_launch(void* const* d_in, const int* in_sizes, int n_in,
                              void* d_out, int out_size, void* d_ws, size_t ws_size,
                              hipStream_t stream) {
  (void)in_sizes; (void)n_in; (void)out_size; (void)ws_size;
  const float* x    = (const float*)d_in[0];
  const float* w    = (const float*)d_in[1];
  const float* bias = (const float*)d_in[2];
  float* out = (float*)d_out;

  ushort* xb = (ushort*)d_ws;                       // 32 MB bf16 x
  ushort* wb = (ushort*)d_ws + (size_t)M * K;       // 4 MB bf16 W (ws >= 36 MB)

  constexpr int conv_blocks = (int)(((size_t)M * K / 8 + (size_t)NS * K / 8) / 256); // 9216
  convert_kernel<<<dim3(conv_blocks), dim3(256), 0, stream>>>(x, w, xb, wb);
  gemm_kernel<<<dim3(MT * NT * SPLITS), dim3(512), 0, stream>>>(xb, wb, out);
  combine_kernel<<<dim3(M * (NS / 4) / 256), dim3(256), 0, stream>>>(bias, out);
}